// Round 4
// baseline (259.215 us; speedup 1.0000x reference)
//
#include <hip/hip_runtime.h>

#define TSEQ 4096
#define DM 512
#define NH 8
#define HS 64
#define CTX 256

typedef __attribute__((ext_vector_type(8))) short bf16x8;
typedef __attribute__((ext_vector_type(4))) float f32x4;
typedef unsigned short u16;
typedef unsigned long long ull;

__device__ __forceinline__ u16 f2bf(float x) {
    unsigned u = __float_as_uint(x);
    unsigned r = (u + 0x7fffu + ((u >> 16) & 1u)) >> 16;
    return (u16)r;
}
__device__ __forceinline__ float bf2f(u16 b) {
    return __uint_as_float(((unsigned)b) << 16);
}
__device__ __forceinline__ void split8(const float* v, bf16x8& h, bf16x8& l) {
    #pragma unroll
    for (int i = 0; i < 8; ++i) {
        u16 hb = f2bf(v[i]);
        float hf = bf2f(hb);
        u16 lb = f2bf(v[i] - hf);
        h[i] = (short)hb;
        l[i] = (short)lb;
    }
}

#define MFMA(a, b, c) __builtin_amdgcn_mfma_f32_16x16x32_bf16((a), (b), (c), 0, 0, 0)

// ---------------------------------------------------------------------------
// Pre-split X: [8192*512] f32 -> Xh, Xl bf16
// ---------------------------------------------------------------------------
__global__ __launch_bounds__(256) void presplit_x(
    const float* __restrict__ X, u16* __restrict__ Xh, u16* __restrict__ Xl)
{
    size_t idx = ((size_t)blockIdx.x * 256 + threadIdx.x) * 8;
    float4 p0 = *(const float4*)(X + idx);
    float4 p1 = *(const float4*)(X + idx + 4);
    float v[8] = {p0.x, p0.y, p0.z, p0.w, p1.x, p1.y, p1.z, p1.w};
    bf16x8 h, l;
    split8(v, h, l);
    *(bf16x8*)(Xh + idx) = h;
    *(bf16x8*)(Xl + idx) = l;
}

// ---------------------------------------------------------------------------
// Pre-split + transpose weights.
// WQ[h][d][s] -> WQt[h][s][d]; WV same; WU[c][d] -> WUt[d][c]. hi/lo bf16.
// ---------------------------------------------------------------------------
__global__ __launch_bounds__(256) void presplit_w(
    const float* __restrict__ WQ, const float* __restrict__ WV,
    const float* __restrict__ WU,
    u16* __restrict__ WQt_h, u16* __restrict__ WQt_l,
    u16* __restrict__ WVt_h, u16* __restrict__ WVt_l,
    u16* __restrict__ WUt_h, u16* __restrict__ WUt_l)
{
    int gidx = blockIdx.x * 256 + threadIdx.x;   // 0 .. 786431
    int a = gidx >> 18;                          // 0: WQ, 1: WV, 2: WU
    int r = gidx & 262143;
    float val;
    u16 *dh, *dl;
    int dst;
    if (a < 2) {
        int h = r >> 15, s = (r >> 9) & 63, d = r & 511;
        const float* W = (a == 0) ? WQ : WV;
        val = W[h * 32768 + d * 64 + s];
        dst = h * 32768 + s * 512 + d;
        dh = (a == 0) ? WQt_h : WVt_h;
        dl = (a == 0) ? WQt_l : WVt_l;
    } else {
        int n = r >> 9, k = r & 511;
        val = WU[k * 512 + n];
        dst = n * 512 + k;
        dh = WUt_h; dl = WUt_l;
    }
    u16 hb = f2bf(val);
    dh[dst] = hb;
    dl[dst] = f2bf(val - bf2f(hb));
}

// ---------------------------------------------------------------------------
// Split-bf16 MFMA GEMM, pre-split inputs. 128x64 tile, K=512, BK=64.
// LDS 48 KB (3 blocks/CU), XOR-swizzled tiles, reg-prefetch of next K-tile.
// mode 0: QV projection (y<8 Q head y prescaled 1/8, else V head y-8).
// mode 1: out projection -> f32 [8192][512].
// ---------------------------------------------------------------------------
__global__ __launch_bounds__(256, 3) void gemm_mfma(
    const u16* __restrict__ Ah_g, const u16* __restrict__ Al_g,
    const u16* __restrict__ B0h, const u16* __restrict__ B0l,
    const u16* __restrict__ B1h, const u16* __restrict__ B1l,
    u16* __restrict__ O0h, u16* __restrict__ O0l,
    u16* __restrict__ O1h, u16* __restrict__ O1l,
    float* __restrict__ Of,
    int mode)
{
    __shared__ u16 Ah[128][64], Al[128][64];
    __shared__ u16 Bh[64][64],  Bl[64][64];

    const int tid = threadIdx.x;
    const int w = tid >> 6, lane = tid & 63;
    const int lg = lane >> 4, ln = lane & 15;
    const int r0 = blockIdx.x * 128;
    const int y = blockIdx.y;

    const u16 *Bsh, *Bsl;
    if (mode == 0) {
        if (y < 8) { Bsh = B0h + (size_t)y * 32768; Bsl = B0l + (size_t)y * 32768; }
        else       { Bsh = B1h + (size_t)(y - 8) * 32768; Bsl = B1l + (size_t)(y - 8) * 32768; }
    } else {
        Bsh = B0h + (size_t)y * 64 * 512;
        Bsl = B0l + (size_t)y * 64 * 512;
    }

    // prefetch registers
    bf16x8 pAh[4], pAl[4], pBh[2], pBl[2];

    #define GEMM_LOAD(k0)                                                   \
        {                                                                   \
            _Pragma("unroll")                                               \
            for (int i2 = 0; i2 < 4; ++i2) {                                \
                int unit = tid + i2 * 256;                                  \
                int row = unit >> 3, kc = unit & 7;                         \
                size_t off = (size_t)(r0 + row) * DM + (k0) + kc * 8;       \
                pAh[i2] = *(const bf16x8*)(Ah_g + off);                     \
                pAl[i2] = *(const bf16x8*)(Al_g + off);                     \
            }                                                               \
            _Pragma("unroll")                                               \
            for (int i2 = 0; i2 < 2; ++i2) {                                \
                int unit = tid + i2 * 256;                                  \
                int n = unit >> 3, kc = unit & 7;                           \
                size_t off = (size_t)n * 512 + (k0) + kc * 8;               \
                pBh[i2] = *(const bf16x8*)(Bsh + off);                      \
                pBl[i2] = *(const bf16x8*)(Bsl + off);                      \
            }                                                               \
        }

    f32x4 acc[2][4];
    #pragma unroll
    for (int i = 0; i < 2; ++i)
        #pragma unroll
        for (int j = 0; j < 4; ++j)
            acc[i][j] = (f32x4){0.f, 0.f, 0.f, 0.f};

    GEMM_LOAD(0);

    for (int kt = 0; kt < 8; ++kt) {
        __syncthreads();   // previous compute done reading LDS
        // write prefetched tile (swizzled cols)
        #pragma unroll
        for (int i2 = 0; i2 < 4; ++i2) {
            int unit = tid + i2 * 256;
            int row = unit >> 3, kc = unit & 7;
            int wcol = (kc * 8) ^ ((row & 7) << 3);
            *(bf16x8*)&Ah[row][wcol] = pAh[i2];
            *(bf16x8*)&Al[row][wcol] = pAl[i2];
        }
        #pragma unroll
        for (int i2 = 0; i2 < 2; ++i2) {
            int unit = tid + i2 * 256;
            int n = unit >> 3, kc = unit & 7;
            int wcol = (kc * 8) ^ ((n & 7) << 3);
            *(bf16x8*)&Bh[n][wcol] = pBh[i2];
            *(bf16x8*)&Bl[n][wcol] = pBl[i2];
        }
        __syncthreads();
        if (kt + 1 < 8) GEMM_LOAD((kt + 1) * 64);

        #pragma unroll
        for (int kk = 0; kk < 2; ++kk) {
            const int fc = (kk * 32 + lg * 8) ^ ((ln & 7) << 3);
            bf16x8 ah[2], al[2], bh2[4], bl2[4];
            #pragma unroll
            for (int ti = 0; ti < 2; ++ti) {
                ah[ti] = *(const bf16x8*)&Ah[w * 32 + ti * 16 + ln][fc];
                al[ti] = *(const bf16x8*)&Al[w * 32 + ti * 16 + ln][fc];
            }
            #pragma unroll
            for (int nj = 0; nj < 4; ++nj) {
                bh2[nj] = *(const bf16x8*)&Bh[nj * 16 + ln][fc];
                bl2[nj] = *(const bf16x8*)&Bl[nj * 16 + ln][fc];
            }
            #pragma unroll
            for (int ti = 0; ti < 2; ++ti)
                #pragma unroll
                for (int nj = 0; nj < 4; ++nj) {
                    acc[ti][nj] = MFMA(ah[ti], bh2[nj], acc[ti][nj]);
                    acc[ti][nj] = MFMA(ah[ti], bl2[nj], acc[ti][nj]);
                    acc[ti][nj] = MFMA(al[ti], bh2[nj], acc[ti][nj]);
                }
        }
    }

    const float qscale = (mode == 0 && y < 8) ? 0.125f : 1.0f;
    #pragma unroll
    for (int ti = 0; ti < 2; ++ti)
        #pragma unroll
        for (int nj = 0; nj < 4; ++nj)
            #pragma unroll
            for (int r = 0; r < 4; ++r) {
                float val = acc[ti][nj][r] * qscale;
                int t = r0 + w * 32 + ti * 16 + lg * 4 + r;
                int n = nj * 16 + ln;
                if (mode == 0) {
                    int bh = (t >> 12) * NH + (y & 7);
                    size_t off = ((size_t)bh * TSEQ + (t & (TSEQ - 1))) * HS + n;
                    u16 hb = f2bf(val);
                    u16 lb = f2bf(val - bf2f(hb));
                    if (y < 8) { O0h[off] = hb; O0l[off] = lb; }
                    else       { O1h[off] = hb; O1l[off] = lb; }
                } else {
                    Of[(size_t)t * DM + y * 64 + n] = val;
                }
            }
}

// ---------------------------------------------------------------------------
// Banded flash attention, split-bf16 MFMA.
// Block: 128 t-rows of one (b,h); 4 waves x (32t x 64u).
// LDS 48 KB (3 blocks/CU): swizzled Vn/Vt [64][64], staggered conflict-free
// transpose, Ps half-strips [128][32] u32, V prefetched one chunk ahead.
// ---------------------------------------------------------------------------
__global__ __launch_bounds__(256, 3) void attn_mfma(
    const u16* __restrict__ Qh_g, const u16* __restrict__ Ql_g,
    const u16* __restrict__ Vh_g, const u16* __restrict__ Vl_g,
    u16* __restrict__ Ch, u16* __restrict__ Cl)
{
    __shared__ u16 Vn_h[64][64], Vn_l[64][64];   // [u][s^((u&7)<<3)]
    __shared__ u16 Vt_h[64][64], Vt_l[64][64];   // [s][u^((s&7)<<3)]
    __shared__ unsigned Ps[128][32];             // [t][(u&31)^((t&7)<<2)] hi|lo<<16

    const int tid = threadIdx.x;
    const int w = tid >> 6, lane = tid & 63;
    const int lg = lane >> 4, ln = lane & 15;
    const int ttile = blockIdx.x & 31;
    const int bh = blockIdx.x >> 5;
    const int t0 = ttile * 128;
    const u16* Qph = Qh_g + (size_t)bh * TSEQ * HS;
    const u16* Qpl = Ql_g + (size_t)bh * TSEQ * HS;
    const u16* Vph = Vh_g + (size_t)bh * TSEQ * HS;
    const u16* Vpl = Vl_g + (size_t)bh * TSEQ * HS;

    // register-resident Q fragments (already prescaled by 1/8 in projection)
    bf16x8 qh[2][2], ql[2][2];
    #pragma unroll
    for (int ti = 0; ti < 2; ++ti)
        #pragma unroll
        for (int kk = 0; kk < 2; ++kk) {
            int trow = t0 + w * 32 + ti * 16 + ln;
            size_t off = (size_t)trow * HS + kk * 32 + lg * 8;
            qh[ti][kk] = *(const bf16x8*)(Qph + off);
            ql[ti][kk] = *(const bf16x8*)(Qpl + off);
        }

    f32x4 o[2][4];
    float m[2][4], lsum[2][4];
    #pragma unroll
    for (int ti = 0; ti < 2; ++ti)
        #pragma unroll
        for (int j = 0; j < 4; ++j) {
            o[ti][j] = (f32x4){0.f, 0.f, 0.f, 0.f};
            m[ti][j] = -1e30f;
            lsum[ti][j] = 0.f;
        }

    int u_lo = t0 - CTX; if (u_lo < 0) u_lo = 0;
    int u_hi = t0 + 128 + CTX; if (u_hi > TSEQ) u_hi = TSEQ;

    // prefetch regs for the V chunk
    bf16x8 pf_h[2], pf_l[2];
    #define V_LOAD(u0v)                                                     \
        {                                                                   \
            _Pragma("unroll")                                               \
            for (int i2 = 0; i2 < 2; ++i2) {                                \
                int unit = tid + i2 * 256;                                  \
                int u = unit >> 3, sc = unit & 7;                           \
                size_t off = (size_t)((u0v) + u) * HS + sc * 8;             \
                pf_h[i2] = *(const bf16x8*)(Vph + off);                     \
                pf_l[i2] = *(const bf16x8*)(Vpl + off);                     \
            }                                                               \
        }

    V_LOAD(u_lo);

    for (int u0 = u_lo; u0 < u_hi; u0 += 64) {
        __syncthreads();   // previous chunk's LDS readers done

        // stage prefetched V chunk: natural (swizzled b128) + transposed
        // (staggered scalar, conflict-free)
        #pragma unroll
        for (int i2 = 0; i2 < 2; ++i2) {
            int unit = tid + i2 * 256;
            int u = unit >> 3, sc = unit & 7;
            bf16x8 h = pf_h[i2], l = pf_l[i2];
            int wcol = (sc * 8) ^ ((u & 7) << 3);
            *(bf16x8*)&Vn_h[u][wcol] = h;
            *(bf16x8*)&Vn_l[u][wcol] = l;
            union { bf16x8 v; ull q[2]; } uh, ul2;
            uh.v = h; ul2.v = l;
            #pragma unroll
            for (int e = 0; e < 8; ++e) {
                int j = (sc + e) & 7;           // stagger: row&7 varies per lane
                ull selh = (j & 4) ? uh.q[1] : uh.q[0];
                ull sell = (j & 4) ? ul2.q[1] : ul2.q[0];
                int sh = (j & 3) * 16;
                int row = sc * 8 + j;
                int col = u ^ (j << 3);         // (row&7) == j
                Vt_h[row][col] = (u16)(selh >> sh);
                Vt_l[row][col] = (u16)(sell >> sh);
            }
        }
        __syncthreads();
        if (u0 + 64 < u_hi) V_LOAD(u0 + 64);   // hide HBM latency under compute

        // scores: S[t][u] = sum_s Q[t][s] V[u][s]
        f32x4 s[2][4];
        #pragma unroll
        for (int ti = 0; ti < 2; ++ti)
            #pragma unroll
            for (int j = 0; j < 4; ++j)
                s[ti][j] = (f32x4){0.f, 0.f, 0.f, 0.f};

        #pragma unroll
        for (int kk = 0; kk < 2; ++kk) {
            const int fc = (kk * 32 + lg * 8) ^ ((ln & 7) << 3);
            bf16x8 vh[4], vl[4];
            #pragma unroll
            for (int uj = 0; uj < 4; ++uj) {
                vh[uj] = *(const bf16x8*)&Vn_h[uj * 16 + ln][fc];
                vl[uj] = *(const bf16x8*)&Vn_l[uj * 16 + ln][fc];
            }
            #pragma unroll
            for (int ti = 0; ti < 2; ++ti)
                #pragma unroll
                for (int uj = 0; uj < 4; ++uj) {
                    s[ti][uj] = MFMA(qh[ti][kk], vh[uj], s[ti][uj]);
                    s[ti][uj] = MFMA(qh[ti][kk], vl[uj], s[ti][uj]);
                    s[ti][uj] = MFMA(ql[ti][kk], vh[uj], s[ti][uj]);
                }
        }

        // band mask
        bool needmask = ((t0 + 127 - u0) > CTX) || ((u0 + 63 - t0) > CTX);
        if (needmask) {
            #pragma unroll
            for (int ti = 0; ti < 2; ++ti)
                #pragma unroll
                for (int uj = 0; uj < 4; ++uj)
                    #pragma unroll
                    for (int r = 0; r < 4; ++r) {
                        int t = t0 + w * 32 + ti * 16 + lg * 4 + r;
                        int u = u0 + uj * 16 + ln;
                        int d = t - u; if (d < 0) d = -d;
                        if (d > CTX) s[ti][uj][r] = -1e30f;
                    }
        }

        // online softmax per row
        float scl[2][4];
        #pragma unroll
        for (int ti = 0; ti < 2; ++ti)
            #pragma unroll
            for (int r = 0; r < 4; ++r) {
                float rm = fmaxf(fmaxf(s[ti][0][r], s[ti][1][r]),
                                 fmaxf(s[ti][2][r], s[ti][3][r]));
                rm = fmaxf(rm, __shfl_xor(rm, 1));
                rm = fmaxf(rm, __shfl_xor(rm, 2));
                rm = fmaxf(rm, __shfl_xor(rm, 4));
                rm = fmaxf(rm, __shfl_xor(rm, 8));
                float mn = fmaxf(m[ti][r], rm);
                float sc = __expf(m[ti][r] - mn);
                m[ti][r] = mn;
                scl[ti][r] = sc;
                float rs = 0.f;
                #pragma unroll
                for (int uj = 0; uj < 4; ++uj) {
                    float p = __expf(s[ti][uj][r] - mn);
                    s[ti][uj][r] = p;
                    rs += p;
                }
                rs += __shfl_xor(rs, 1);
                rs += __shfl_xor(rs, 2);
                rs += __shfl_xor(rs, 4);
                rs += __shfl_xor(rs, 8);
                lsum[ti][r] = lsum[ti][r] * sc + rs;
            }

        // rescale running O
        #pragma unroll
        for (int ti = 0; ti < 2; ++ti)
            #pragma unroll
            for (int sj = 0; sj < 4; ++sj)
                #pragma unroll
                for (int r = 0; r < 4; ++r)
                    o[ti][sj][r] *= scl[ti][r];

        // PV in two u-halves; P half-strip written then consumed by same wave
        #pragma unroll
        for (int kk = 0; kk < 2; ++kk) {
            #pragma unroll
            for (int ti = 0; ti < 2; ++ti)
                #pragma unroll
                for (int u2 = 0; u2 < 2; ++u2) {
                    int uj = kk * 2 + u2;
                    #pragma unroll
                    for (int r = 0; r < 4; ++r) {
                        float p = s[ti][uj][r];
                        u16 hb = f2bf(p);
                        u16 lb = f2bf(p - bf2f(hb));
                        int trow = w * 32 + ti * 16 + lg * 4 + r;
                        int ucol = (u2 * 16 + ln) ^ ((trow & 7) << 2);
                        Ps[trow][ucol] = (unsigned)hb | ((unsigned)lb << 16);
                    }
                }

            bf16x8 ph[2], pl[2], vth[4], vtl[4];
            #pragma unroll
            for (int ti = 0; ti < 2; ++ti) {
                int prow = w * 32 + ti * 16 + ln;
                int sw = (ln & 7) << 2;
                uint4 q0 = *(const uint4*)&Ps[prow][(lg * 8) ^ sw];
                uint4 q1 = *(const uint4*)&Ps[prow][(lg * 8 + 4) ^ sw];
                union { unsigned u[4]; bf16x8 v; } H, L;
                H.u[0] = __builtin_amdgcn_perm(q0.y, q0.x, 0x05040100u);
                H.u[1] = __builtin_amdgcn_perm(q0.w, q0.z, 0x05040100u);
                H.u[2] = __builtin_amdgcn_perm(q1.y, q1.x, 0x05040100u);
                H.u[3] = __builtin_amdgcn_perm(q1.w, q1.z, 0x05040100u);
                L.u[0] = __builtin_amdgcn_perm(q0.y, q0.x, 0x07060302u);
                L.u[1] = __builtin_amdgcn_perm(q0.w, q0.z, 0x07060302u);
                L.u[2] = __builtin_amdgcn_perm(q1.y, q1.x, 0x07060302u);
                L.u[3] = __builtin_amdgcn_perm(q1.w, q1.z, 0x07060302u);
                ph[ti] = H.v;
                pl[ti] = L.v;
            }
            const int fct = (kk * 32 + lg * 8) ^ ((ln & 7) << 3);
            #pragma unroll
            for (int sj = 0; sj < 4; ++sj) {
                vth[sj] = *(const bf16x8*)&Vt_h[sj * 16 + ln][fct];
                vtl[sj] = *(const bf16x8*)&Vt_l[sj * 16 + ln][fct];
            }
            #pragma unroll
            for (int ti = 0; ti < 2; ++ti)
                #pragma unroll
                for (int sj = 0; sj < 4; ++sj) {
                    o[ti][sj] = MFMA(ph[ti], vth[sj], o[ti][sj]);
                    o[ti][sj] = MFMA(ph[ti], vtl[sj], o[ti][sj]);
                    o[ti][sj] = MFMA(pl[ti], vth[sj], o[ti][sj]);
                }
        }
    }

    // epilogue: C as split bf16, layout [b][t][h*64+s]
    const int b = bh >> 3, h = bh & 7;
    #pragma unroll
    for (int ti = 0; ti < 2; ++ti)
        #pragma unroll
        for (int r = 0; r < 4; ++r) {
            float inv = 1.f / lsum[ti][r];
            int t = t0 + w * 32 + ti * 16 + lg * 4 + r;
            #pragma unroll
            for (int sj = 0; sj < 4; ++sj) {
                int ss = sj * 16 + ln;
                float val = o[ti][sj][r] * inv;
                size_t off = ((size_t)(b * TSEQ + t)) * DM + h * HS + ss;
                u16 hb = f2bf(val);
                Ch[off] = hb;
                Cl[off] = f2bf(val - bf2f(hb));
            }
        }
}

// ---------------------------------------------------------------------------
extern "C" void kernel_launch(void* const* d_in, const int* in_sizes, int n_in,
                              void* d_out, int out_size, void* d_ws, size_t ws_size,
                              hipStream_t stream) {
    const float* X  = (const float*)d_in[0];
    const float* WQ = (const float*)d_in[1];
    const float* WV = (const float*)d_in[2];
    const float* WU = (const float*)d_in[3];
    float* out = (float*)d_out;

    const size_t SZ = 8388608;   // 8 MB region
    char* ws = (char*)d_ws;
    u16* Xh = (u16*)(ws);             // later reused as Ch
    u16* Xl = (u16*)(ws + SZ);        // later reused as Cl
    u16* Qh = (u16*)(ws + 2 * SZ);
    u16* Ql = (u16*)(ws + 3 * SZ);
    u16* Vh = (u16*)(ws + 4 * SZ);
    u16* Vl = (u16*)(ws + 5 * SZ);
    char* wsw = ws + 6 * SZ;
    u16* WQt_h = (u16*)(wsw);
    u16* WQt_l = (u16*)(wsw + 524288);
    u16* WVt_h = (u16*)(wsw + 2 * 524288);
    u16* WVt_l = (u16*)(wsw + 3 * 524288);
    u16* WUt_h = (u16*)(wsw + 4 * 524288);
    u16* WUt_l = (u16*)(wsw + 5 * 524288);

    presplit_x<<<2048, 256, 0, stream>>>(X, Xh, Xl);
    presplit_w<<<3072, 256, 0, stream>>>(WQ, WV, WU, WQt_h, WQt_l,
                                         WVt_h, WVt_l, WUt_h, WUt_l);
    gemm_mfma<<<dim3(64, 16), 256, 0, stream>>>(
        Xh, Xl, WQt_h, WQt_l, WVt_h, WVt_l, Qh, Ql, Vh, Vl, nullptr, 0);
    attn_mfma<<<dim3(512), 256, 0, stream>>>(Qh, Ql, Vh, Vl, Xh, Xl);
    gemm_mfma<<<dim3(64, 8), 256, 0, stream>>>(
        Xh, Xl, WUt_h, WUt_l, nullptr, nullptr,
        nullptr, nullptr, nullptr, nullptr, out, 1);
}

// Round 5
// 249.763 us; speedup vs baseline: 1.0378x; 1.0378x over previous
//
#include <hip/hip_runtime.h>

#define TSEQ 4096
#define DM 512
#define NH 8
#define HS 64
#define CTX 256

typedef __attribute__((ext_vector_type(8))) short bf16x8;
typedef __attribute__((ext_vector_type(4))) float f32x4;
typedef unsigned short u16;
typedef unsigned long long ull;

__device__ __forceinline__ u16 f2bf(float x) {
    unsigned u = __float_as_uint(x);
    unsigned r = (u + 0x7fffu + ((u >> 16) & 1u)) >> 16;
    return (u16)r;
}
__device__ __forceinline__ float bf2f(u16 b) {
    return __uint_as_float(((unsigned)b) << 16);
}
__device__ __forceinline__ void split8(const float* v, bf16x8& h, bf16x8& l) {
    #pragma unroll
    for (int i = 0; i < 8; ++i) {
        u16 hb = f2bf(v[i]);
        float hf = bf2f(hb);
        u16 lb = f2bf(v[i] - hf);
        h[i] = (short)hb;
        l[i] = (short)lb;
    }
}

#define MFMA(a, b, c) __builtin_amdgcn_mfma_f32_16x16x32_bf16((a), (b), (c), 0, 0, 0)

// ---------------------------------------------------------------------------
__global__ __launch_bounds__(256) void presplit_x(
    const float* __restrict__ X, u16* __restrict__ Xh, u16* __restrict__ Xl)
{
    size_t idx = ((size_t)blockIdx.x * 256 + threadIdx.x) * 8;
    float4 p0 = *(const float4*)(X + idx);
    float4 p1 = *(const float4*)(X + idx + 4);
    float v[8] = {p0.x, p0.y, p0.z, p0.w, p1.x, p1.y, p1.z, p1.w};
    bf16x8 h, l;
    split8(v, h, l);
    *(bf16x8*)(Xh + idx) = h;
    *(bf16x8*)(Xl + idx) = l;
}

// ---------------------------------------------------------------------------
__global__ __launch_bounds__(256) void presplit_w(
    const float* __restrict__ WQ, const float* __restrict__ WV,
    const float* __restrict__ WU,
    u16* __restrict__ WQt_h, u16* __restrict__ WQt_l,
    u16* __restrict__ WVt_h, u16* __restrict__ WVt_l,
    u16* __restrict__ WUt_h, u16* __restrict__ WUt_l)
{
    int gidx = blockIdx.x * 256 + threadIdx.x;   // 0 .. 786431
    int a = gidx >> 18;                          // 0: WQ, 1: WV, 2: WU
    int r = gidx & 262143;
    float val;
    u16 *dh, *dl;
    int dst;
    if (a < 2) {
        int h = r >> 15, s = (r >> 9) & 63, d = r & 511;
        const float* W = (a == 0) ? WQ : WV;
        val = W[h * 32768 + d * 64 + s];
        dst = h * 32768 + s * 512 + d;
        dh = (a == 0) ? WQt_h : WVt_h;
        dl = (a == 0) ? WQt_l : WVt_l;
    } else {
        int n = r >> 9, k = r & 511;
        val = WU[k * 512 + n];
        dst = n * 512 + k;
        dh = WUt_h; dl = WUt_l;
    }
    u16 hb = f2bf(val);
    dh[dst] = hb;
    dl[dst] = f2bf(val - bf2f(hb));
}

// ---------------------------------------------------------------------------
// Split-bf16 MFMA GEMM. 128x64 tile, K=512, BK=64, 48 KB LDS, XOR swizzle,
// reg-prefetch of next K-tile via NAMED scalars (no spillable arrays).
// ---------------------------------------------------------------------------
__global__ __launch_bounds__(256, 3) void gemm_mfma(
    const u16* __restrict__ Ah_g, const u16* __restrict__ Al_g,
    const u16* __restrict__ B0h, const u16* __restrict__ B0l,
    const u16* __restrict__ B1h, const u16* __restrict__ B1l,
    u16* __restrict__ O0h, u16* __restrict__ O0l,
    u16* __restrict__ O1h, u16* __restrict__ O1l,
    float* __restrict__ Of,
    int mode)
{
    __shared__ u16 Ah[128][64], Al[128][64];
    __shared__ u16 Bh[64][64],  Bl[64][64];

    const int tid = threadIdx.x;
    const int w = tid >> 6, lane = tid & 63;
    const int lg = lane >> 4, ln = lane & 15;
    const int r0 = blockIdx.x * 128;
    const int y = blockIdx.y;

    const u16 *Bsh, *Bsl;
    if (mode == 0) {
        if (y < 8) { Bsh = B0h + (size_t)y * 32768; Bsl = B0l + (size_t)y * 32768; }
        else       { Bsh = B1h + (size_t)(y - 8) * 32768; Bsl = B1l + (size_t)(y - 8) * 32768; }
    } else {
        Bsh = B0h + (size_t)y * 64 * 512;
        Bsl = B0l + (size_t)y * 64 * 512;
    }

    // staging geometry: i2-invariant pieces
    const int r_a = tid >> 3;           // 0..31
    const int kc  = tid & 7;            // 0..7
    const int wcol = (kc * 8) ^ ((r_a & 7) << 3);
    const size_t gA = (size_t)(r0 + r_a) * DM + kc * 8;
    const size_t gB = (size_t)r_a * 512 + kc * 8;

    // named prefetch registers
    bf16x8 a0h, a1h, a2h, a3h, a0l, a1l, a2l, a3l, b0h, b1h, b0l, b1l;

    #define GLOAD(k0)                                                   \
        a0h = *(const bf16x8*)(Ah_g + gA + (k0));                       \
        a1h = *(const bf16x8*)(Ah_g + gA + 32 * DM + (k0));             \
        a2h = *(const bf16x8*)(Ah_g + gA + 64 * DM + (k0));             \
        a3h = *(const bf16x8*)(Ah_g + gA + 96 * DM + (k0));             \
        a0l = *(const bf16x8*)(Al_g + gA + (k0));                       \
        a1l = *(const bf16x8*)(Al_g + gA + 32 * DM + (k0));             \
        a2l = *(const bf16x8*)(Al_g + gA + 64 * DM + (k0));             \
        a3l = *(const bf16x8*)(Al_g + gA + 96 * DM + (k0));             \
        b0h = *(const bf16x8*)(Bsh + gB + (k0));                        \
        b1h = *(const bf16x8*)(Bsh + gB + 32 * 512 + (k0));             \
        b0l = *(const bf16x8*)(Bsl + gB + (k0));                        \
        b1l = *(const bf16x8*)(Bsl + gB + 32 * 512 + (k0));

    f32x4 acc[2][4];
    #pragma unroll
    for (int i = 0; i < 2; ++i)
        #pragma unroll
        for (int j = 0; j < 4; ++j)
            acc[i][j] = (f32x4){0.f, 0.f, 0.f, 0.f};

    GLOAD(0);

    for (int kt = 0; kt < 8; ++kt) {
        __syncthreads();
        *(bf16x8*)&Ah[r_a][wcol]      = a0h;
        *(bf16x8*)&Ah[r_a + 32][wcol] = a1h;
        *(bf16x8*)&Ah[r_a + 64][wcol] = a2h;
        *(bf16x8*)&Ah[r_a + 96][wcol] = a3h;
        *(bf16x8*)&Al[r_a][wcol]      = a0l;
        *(bf16x8*)&Al[r_a + 32][wcol] = a1l;
        *(bf16x8*)&Al[r_a + 64][wcol] = a2l;
        *(bf16x8*)&Al[r_a + 96][wcol] = a3l;
        *(bf16x8*)&Bh[r_a][wcol]      = b0h;
        *(bf16x8*)&Bh[r_a + 32][wcol] = b1h;
        *(bf16x8*)&Bl[r_a][wcol]      = b0l;
        *(bf16x8*)&Bl[r_a + 32][wcol] = b1l;
        __syncthreads();
        if (kt < 7) { GLOAD((kt + 1) * 64); }

        #pragma unroll
        for (int kk = 0; kk < 2; ++kk) {
            const int fc = (kk * 32 + lg * 8) ^ ((ln & 7) << 3);
            bf16x8 ah[2], al[2], bh2[4], bl2[4];
            #pragma unroll
            for (int ti = 0; ti < 2; ++ti) {
                ah[ti] = *(const bf16x8*)&Ah[w * 32 + ti * 16 + ln][fc];
                al[ti] = *(const bf16x8*)&Al[w * 32 + ti * 16 + ln][fc];
            }
            #pragma unroll
            for (int nj = 0; nj < 4; ++nj) {
                bh2[nj] = *(const bf16x8*)&Bh[nj * 16 + ln][fc];
                bl2[nj] = *(const bf16x8*)&Bl[nj * 16 + ln][fc];
            }
            #pragma unroll
            for (int ti = 0; ti < 2; ++ti)
                #pragma unroll
                for (int nj = 0; nj < 4; ++nj) {
                    acc[ti][nj] = MFMA(ah[ti], bh2[nj], acc[ti][nj]);
                    acc[ti][nj] = MFMA(ah[ti], bl2[nj], acc[ti][nj]);
                    acc[ti][nj] = MFMA(al[ti], bh2[nj], acc[ti][nj]);
                }
        }
    }
    #undef GLOAD

    const float qscale = (mode == 0 && y < 8) ? 0.125f : 1.0f;
    #pragma unroll
    for (int ti = 0; ti < 2; ++ti)
        #pragma unroll
        for (int nj = 0; nj < 4; ++nj)
            #pragma unroll
            for (int r = 0; r < 4; ++r) {
                float val = acc[ti][nj][r] * qscale;
                int t = r0 + w * 32 + ti * 16 + lg * 4 + r;
                int n = nj * 16 + ln;
                if (mode == 0) {
                    int bh = (t >> 12) * NH + (y & 7);
                    size_t off = ((size_t)bh * TSEQ + (t & (TSEQ - 1))) * HS + n;
                    u16 hb = f2bf(val);
                    u16 lb = f2bf(val - bf2f(hb));
                    if (y < 8) { O0h[off] = hb; O0l[off] = lb; }
                    else       { O1h[off] = hb; O1l[off] = lb; }
                } else {
                    Of[(size_t)t * DM + y * 64 + n] = val;
                }
            }
}

// ---------------------------------------------------------------------------
// Banded flash attention. 128 t-rows/block, 4 waves. 48 KB LDS, swizzled,
// staggered conflict-free transpose, V prefetch in NAMED scalar regs.
// ---------------------------------------------------------------------------
__global__ __launch_bounds__(256, 3) void attn_mfma(
    const u16* __restrict__ Qh_g, const u16* __restrict__ Ql_g,
    const u16* __restrict__ Vh_g, const u16* __restrict__ Vl_g,
    u16* __restrict__ Ch, u16* __restrict__ Cl)
{
    __shared__ u16 Vn_h[64][64], Vn_l[64][64];   // [u][s^((u&7)<<3)]
    __shared__ u16 Vt_h[64][64], Vt_l[64][64];   // [s][u^((s&7)<<3)]
    __shared__ unsigned Ps[128][32];             // [t][(u&31)^((t&7)<<2)]

    const int tid = threadIdx.x;
    const int w = tid >> 6, lane = tid & 63;
    const int lg = lane >> 4, ln = lane & 15;
    const int ttile = blockIdx.x & 31;
    const int bh = blockIdx.x >> 5;
    const int t0 = ttile * 128;
    const u16* Qph = Qh_g + (size_t)bh * TSEQ * HS;
    const u16* Qpl = Ql_g + (size_t)bh * TSEQ * HS;
    const u16* Vph = Vh_g + (size_t)bh * TSEQ * HS;
    const u16* Vpl = Vl_g + (size_t)bh * TSEQ * HS;

    // register-resident Q fragments (prescaled by 1/8 in projection)
    bf16x8 qh[2][2], ql[2][2];
    #pragma unroll
    for (int ti = 0; ti < 2; ++ti)
        #pragma unroll
        for (int kk = 0; kk < 2; ++kk) {
            int trow = t0 + w * 32 + ti * 16 + ln;
            size_t off = (size_t)trow * HS + kk * 32 + lg * 8;
            qh[ti][kk] = *(const bf16x8*)(Qph + off);
            ql[ti][kk] = *(const bf16x8*)(Qpl + off);
        }

    f32x4 o[2][4];
    float m[2][4], lsum[2][4];
    #pragma unroll
    for (int ti = 0; ti < 2; ++ti)
        #pragma unroll
        for (int j = 0; j < 4; ++j) {
            o[ti][j] = (f32x4){0.f, 0.f, 0.f, 0.f};
            m[ti][j] = -1e30f;
            lsum[ti][j] = 0.f;
        }

    int u_lo = t0 - CTX; if (u_lo < 0) u_lo = 0;
    int u_hi = t0 + 128 + CTX; if (u_hi > TSEQ) u_hi = TSEQ;

    // staging geometry (i2-invariant): u = u_r + {0,32}, sc = tid&7
    const int u_r = tid >> 3;           // 0..31
    const int sc  = tid & 7;            // 0..7
    const size_t gV = (size_t)u_r * HS + sc * 8;

    bf16x8 vf0h, vf1h, vf0l, vf1l;       // named prefetch regs
    #define V_LOAD(u0v)                                                   \
        vf0h = *(const bf16x8*)(Vph + (size_t)(u0v) * HS + gV);           \
        vf1h = *(const bf16x8*)(Vph + (size_t)(u0v) * HS + gV + 32 * HS); \
        vf0l = *(const bf16x8*)(Vpl + (size_t)(u0v) * HS + gV);           \
        vf1l = *(const bf16x8*)(Vpl + (size_t)(u0v) * HS + gV + 32 * HS);

    V_LOAD(u_lo);

    const int wcolV = (sc * 8) ^ ((u_r & 7) << 3);

    for (int u0 = u_lo; u0 < u_hi; u0 += 64) {
        __syncthreads();

        // natural layout writes (swizzled b128)
        *(bf16x8*)&Vn_h[u_r][wcolV]      = vf0h;
        *(bf16x8*)&Vn_h[u_r + 32][wcolV] = vf1h;
        *(bf16x8*)&Vn_l[u_r][wcolV]      = vf0l;
        *(bf16x8*)&Vn_l[u_r + 32][wcolV] = vf1l;
        // transposed writes, staggered (conflict-free): row&7 == j
        {
            union { bf16x8 v; ull q[2]; } h0, h1, l0, l1;
            h0.v = vf0h; h1.v = vf1h; l0.v = vf0l; l1.v = vf1l;
            #pragma unroll
            for (int e = 0; e < 8; ++e) {
                int j = (sc + e) & 7;
                int sh = (j & 3) * 16;
                int row = sc * 8 + j;
                ull sh0 = (j & 4) ? h0.q[1] : h0.q[0];
                ull sl0 = (j & 4) ? l0.q[1] : l0.q[0];
                ull sh1 = (j & 4) ? h1.q[1] : h1.q[0];
                ull sl1 = (j & 4) ? l1.q[1] : l1.q[0];
                Vt_h[row][u_r ^ (j << 3)]        = (u16)(sh0 >> sh);
                Vt_l[row][u_r ^ (j << 3)]        = (u16)(sl0 >> sh);
                Vt_h[row][(u_r + 32) ^ (j << 3)] = (u16)(sh1 >> sh);
                Vt_l[row][(u_r + 32) ^ (j << 3)] = (u16)(sl1 >> sh);
            }
        }
        __syncthreads();
        if (u0 + 64 < u_hi) { V_LOAD(u0 + 64); }   // hide HBM under compute

        // scores: S[t][u] = sum_s Q[t][s] V[u][s]
        f32x4 s[2][4];
        #pragma unroll
        for (int ti = 0; ti < 2; ++ti)
            #pragma unroll
            for (int j = 0; j < 4; ++j)
                s[ti][j] = (f32x4){0.f, 0.f, 0.f, 0.f};

        #pragma unroll
        for (int kk = 0; kk < 2; ++kk) {
            const int fc = (kk * 32 + lg * 8) ^ ((ln & 7) << 3);
            bf16x8 vh[4], vl[4];
            #pragma unroll
            for (int uj = 0; uj < 4; ++uj) {
                vh[uj] = *(const bf16x8*)&Vn_h[uj * 16 + ln][fc];
                vl[uj] = *(const bf16x8*)&Vn_l[uj * 16 + ln][fc];
            }
            #pragma unroll
            for (int ti = 0; ti < 2; ++ti)
                #pragma unroll
                for (int uj = 0; uj < 4; ++uj) {
                    s[ti][uj] = MFMA(qh[ti][kk], vh[uj], s[ti][uj]);
                    s[ti][uj] = MFMA(qh[ti][kk], vl[uj], s[ti][uj]);
                    s[ti][uj] = MFMA(ql[ti][kk], vh[uj], s[ti][uj]);
                }
        }

        // band mask
        bool needmask = ((t0 + 127 - u0) > CTX) || ((u0 + 63 - t0) > CTX);
        if (needmask) {
            #pragma unroll
            for (int ti = 0; ti < 2; ++ti)
                #pragma unroll
                for (int uj = 0; uj < 4; ++uj)
                    #pragma unroll
                    for (int r = 0; r < 4; ++r) {
                        int t = t0 + w * 32 + ti * 16 + lg * 4 + r;
                        int u = u0 + uj * 16 + ln;
                        int d = t - u; if (d < 0) d = -d;
                        if (d > CTX) s[ti][uj][r] = -1e30f;
                    }
        }

        // online softmax per row
        float scl[2][4];
        #pragma unroll
        for (int ti = 0; ti < 2; ++ti)
            #pragma unroll
            for (int r = 0; r < 4; ++r) {
                float rm = fmaxf(fmaxf(s[ti][0][r], s[ti][1][r]),
                                 fmaxf(s[ti][2][r], s[ti][3][r]));
                rm = fmaxf(rm, __shfl_xor(rm, 1));
                rm = fmaxf(rm, __shfl_xor(rm, 2));
                rm = fmaxf(rm, __shfl_xor(rm, 4));
                rm = fmaxf(rm, __shfl_xor(rm, 8));
                float mn = fmaxf(m[ti][r], rm);
                float sc2 = __expf(m[ti][r] - mn);
                m[ti][r] = mn;
                scl[ti][r] = sc2;
                float rs = 0.f;
                #pragma unroll
                for (int uj = 0; uj < 4; ++uj) {
                    float p = __expf(s[ti][uj][r] - mn);
                    s[ti][uj][r] = p;
                    rs += p;
                }
                rs += __shfl_xor(rs, 1);
                rs += __shfl_xor(rs, 2);
                rs += __shfl_xor(rs, 4);
                rs += __shfl_xor(rs, 8);
                lsum[ti][r] = lsum[ti][r] * sc2 + rs;
            }

        // rescale running O
        #pragma unroll
        for (int ti = 0; ti < 2; ++ti)
            #pragma unroll
            for (int sj = 0; sj < 4; ++sj)
                #pragma unroll
                for (int r = 0; r < 4; ++r)
                    o[ti][sj][r] *= scl[ti][r];

        // PV in two u-halves; P half-strip written then consumed by same wave
        #pragma unroll
        for (int kk = 0; kk < 2; ++kk) {
            #pragma unroll
            for (int ti = 0; ti < 2; ++ti)
                #pragma unroll
                for (int u2 = 0; u2 < 2; ++u2) {
                    int uj = kk * 2 + u2;
                    #pragma unroll
                    for (int r = 0; r < 4; ++r) {
                        float p = s[ti][uj][r];
                        u16 hb = f2bf(p);
                        u16 lb = f2bf(p - bf2f(hb));
                        int trow = w * 32 + ti * 16 + lg * 4 + r;
                        int ucol = (u2 * 16 + ln) ^ ((trow & 7) << 2);
                        Ps[trow][ucol] = (unsigned)hb | ((unsigned)lb << 16);
                    }
                }

            bf16x8 ph[2], pl[2], vth[4], vtl[4];
            #pragma unroll
            for (int ti = 0; ti < 2; ++ti) {
                int prow = w * 32 + ti * 16 + ln;
                int sw = (ln & 7) << 2;
                uint4 q0 = *(const uint4*)&Ps[prow][(lg * 8) ^ sw];
                uint4 q1 = *(const uint4*)&Ps[prow][(lg * 8 + 4) ^ sw];
                union { unsigned u[4]; bf16x8 v; } H, L;
                H.u[0] = __builtin_amdgcn_perm(q0.y, q0.x, 0x05040100u);
                H.u[1] = __builtin_amdgcn_perm(q0.w, q0.z, 0x05040100u);
                H.u[2] = __builtin_amdgcn_perm(q1.y, q1.x, 0x05040100u);
                H.u[3] = __builtin_amdgcn_perm(q1.w, q1.z, 0x05040100u);
                L.u[0] = __builtin_amdgcn_perm(q0.y, q0.x, 0x07060302u);
                L.u[1] = __builtin_amdgcn_perm(q0.w, q0.z, 0x07060302u);
                L.u[2] = __builtin_amdgcn_perm(q1.y, q1.x, 0x07060302u);
                L.u[3] = __builtin_amdgcn_perm(q1.w, q1.z, 0x07060302u);
                ph[ti] = H.v;
                pl[ti] = L.v;
            }
            const int fct = (kk * 32 + lg * 8) ^ ((ln & 7) << 3);
            #pragma unroll
            for (int sj = 0; sj < 4; ++sj) {
                vth[sj] = *(const bf16x8*)&Vt_h[sj * 16 + ln][fct];
                vtl[sj] = *(const bf16x8*)&Vt_l[sj * 16 + ln][fct];
            }
            #pragma unroll
            for (int ti = 0; ti < 2; ++ti)
                #pragma unroll
                for (int sj = 0; sj < 4; ++sj) {
                    o[ti][sj] = MFMA(ph[ti], vth[sj], o[ti][sj]);
                    o[ti][sj] = MFMA(ph[ti], vtl[sj], o[ti][sj]);
                    o[ti][sj] = MFMA(pl[ti], vth[sj], o[ti][sj]);
                }
        }
    }
    #undef V_LOAD

    // epilogue: C as split bf16, layout [b][t][h*64+s]
    const int b = bh >> 3, h = bh & 7;
    #pragma unroll
    for (int ti = 0; ti < 2; ++ti)
        #pragma unroll
        for (int r = 0; r < 4; ++r) {
            float inv = 1.f / lsum[ti][r];
            int t = t0 + w * 32 + ti * 16 + lg * 4 + r;
            #pragma unroll
            for (int sj = 0; sj < 4; ++sj) {
                int ss = sj * 16 + ln;
                float val = o[ti][sj][r] * inv;
                size_t off = ((size_t)(b * TSEQ + t)) * DM + h * HS + ss;
                u16 hb = f2bf(val);
                Ch[off] = hb;
                Cl[off] = f2bf(val - bf2f(hb));
            }
        }
}

// ---------------------------------------------------------------------------
extern "C" void kernel_launch(void* const* d_in, const int* in_sizes, int n_in,
                              void* d_out, int out_size, void* d_ws, size_t ws_size,
                              hipStream_t stream) {
    const float* X  = (const float*)d_in[0];
    const float* WQ = (const float*)d_in[1];
    const float* WV = (const float*)d_in[2];
    const float* WU = (const float*)d_in[3];
    float* out = (float*)d_out;

    const size_t SZ = 8388608;   // 8 MB region
    char* ws = (char*)d_ws;
    u16* Xh = (u16*)(ws);             // later reused as Ch
    u16* Xl = (u16*)(ws + SZ);        // later reused as Cl
    u16* Qh = (u16*)(ws + 2 * SZ);
    u16* Ql = (u16*)(ws + 3 * SZ);
    u16* Vh = (u16*)(ws + 4 * SZ);
    u16* Vl = (u16*)(ws + 5 * SZ);
    char* wsw = ws + 6 * SZ;
    u16* WQt_h = (u16*)(wsw);
    u16* WQt_l = (u16*)(wsw + 524288);
    u16* WVt_h = (u16*)(wsw + 2 * 524288);
    u16* WVt_l = (u16*)(wsw + 3 * 524288);
    u16* WUt_h = (u16*)(wsw + 4 * 524288);
    u16* WUt_l = (u16*)(wsw + 5 * 524288);

    presplit_x<<<2048, 256, 0, stream>>>(X, Xh, Xl);
    presplit_w<<<3072, 256, 0, stream>>>(WQ, WV, WU, WQt_h, WQt_l,
                                         WVt_h, WVt_l, WUt_h, WUt_l);
    gemm_mfma<<<dim3(64, 16), 256, 0, stream>>>(
        Xh, Xl, WQt_h, WQt_l, WVt_h, WVt_l, Qh, Ql, Vh, Vl, nullptr, 0);
    attn_mfma<<<dim3(512), 256, 0, stream>>>(Qh, Ql, Vh, Vl, Xh, Xl);
    gemm_mfma<<<dim3(64, 8), 256, 0, stream>>>(
        Xh, Xl, WUt_h, WUt_l, nullptr, nullptr,
        nullptr, nullptr, nullptr, nullptr, out, 1);
}

// Round 6
// 152.856 us; speedup vs baseline: 1.6958x; 1.6340x over previous
//
#include <hip/hip_runtime.h>

#define TSEQ 4096
#define DM 512
#define NH 8
#define HS 64
#define CTX 256

typedef __attribute__((ext_vector_type(8))) short bf16x8;
typedef __attribute__((ext_vector_type(4))) float f32x4;
typedef unsigned short u16;
typedef unsigned long long ull;

__device__ __forceinline__ u16 f2bf(float x) {
    unsigned u = __float_as_uint(x);
    unsigned r = (u + 0x7fffu + ((u >> 16) & 1u)) >> 16;
    return (u16)r;
}
__device__ __forceinline__ float bf2f(u16 b) {
    return __uint_as_float(((unsigned)b) << 16);
}
__device__ __forceinline__ void split8(const float* v, bf16x8& h, bf16x8& l) {
    #pragma unroll
    for (int i = 0; i < 8; ++i) {
        u16 hb = f2bf(v[i]);
        float hf = bf2f(hb);
        u16 lb = f2bf(v[i] - hf);
        h[i] = (short)hb;
        l[i] = (short)lb;
    }
}

#define MFMA(a, b, c) __builtin_amdgcn_mfma_f32_16x16x32_bf16((a), (b), (c), 0, 0, 0)

// ---------------------------------------------------------------------------
__global__ __launch_bounds__(256) void presplit_x(
    const float* __restrict__ X, u16* __restrict__ Xh, u16* __restrict__ Xl)
{
    size_t idx = ((size_t)blockIdx.x * 256 + threadIdx.x) * 8;
    float4 p0 = *(const float4*)(X + idx);
    float4 p1 = *(const float4*)(X + idx + 4);
    float v[8] = {p0.x, p0.y, p0.z, p0.w, p1.x, p1.y, p1.z, p1.w};
    bf16x8 h, l;
    split8(v, h, l);
    *(bf16x8*)(Xh + idx) = h;
    *(bf16x8*)(Xl + idx) = l;
}

// ---------------------------------------------------------------------------
__global__ __launch_bounds__(256) void presplit_w(
    const float* __restrict__ WQ, const float* __restrict__ WV,
    const float* __restrict__ WU,
    u16* __restrict__ WQt_h, u16* __restrict__ WQt_l,
    u16* __restrict__ WVt_h, u16* __restrict__ WVt_l,
    u16* __restrict__ WUt_h, u16* __restrict__ WUt_l)
{
    int gidx = blockIdx.x * 256 + threadIdx.x;   // 0 .. 786431
    int a = gidx >> 18;                          // 0: WQ, 1: WV, 2: WU
    int r = gidx & 262143;
    float val;
    u16 *dh, *dl;
    int dst;
    if (a < 2) {
        int h = r >> 15, s = (r >> 9) & 63, d = r & 511;
        const float* W = (a == 0) ? WQ : WV;
        val = W[h * 32768 + d * 64 + s];
        dst = h * 32768 + s * 512 + d;
        dh = (a == 0) ? WQt_h : WVt_h;
        dl = (a == 0) ? WQt_l : WVt_l;
    } else {
        int n = r >> 9, k = r & 511;
        val = WU[k * 512 + n];
        dst = n * 512 + k;
        dh = WUt_h; dl = WUt_l;
    }
    u16 hb = f2bf(val);
    dh[dst] = hb;
    dl[dst] = f2bf(val - bf2f(hb));
}

// ---------------------------------------------------------------------------
// Split-bf16 MFMA GEMM. 128x64 tile, K=512, BK=64, 48 KB LDS, XOR swizzle,
// reg-prefetch of next K-tile via named scalars. No occupancy floor (a
// __launch_bounds__ min-occupancy arg forced VGPR=84 + spills in R4/R5).
// ---------------------------------------------------------------------------
__global__ __launch_bounds__(256) void gemm_mfma(
    const u16* __restrict__ Ah_g, const u16* __restrict__ Al_g,
    const u16* __restrict__ B0h, const u16* __restrict__ B0l,
    const u16* __restrict__ B1h, const u16* __restrict__ B1l,
    u16* __restrict__ O0h, u16* __restrict__ O0l,
    u16* __restrict__ O1h, u16* __restrict__ O1l,
    float* __restrict__ Of,
    int mode)
{
    __shared__ u16 Ah[128][64], Al[128][64];
    __shared__ u16 Bh[64][64],  Bl[64][64];

    const int tid = threadIdx.x;
    const int w = tid >> 6, lane = tid & 63;
    const int lg = lane >> 4, ln = lane & 15;
    const int r0 = blockIdx.x * 128;
    const int y = blockIdx.y;

    const u16 *Bsh, *Bsl;
    if (mode == 0) {
        if (y < 8) { Bsh = B0h + (size_t)y * 32768; Bsl = B0l + (size_t)y * 32768; }
        else       { Bsh = B1h + (size_t)(y - 8) * 32768; Bsl = B1l + (size_t)(y - 8) * 32768; }
    } else {
        Bsh = B0h + (size_t)y * 64 * 512;
        Bsl = B0l + (size_t)y * 64 * 512;
    }

    // staging geometry: iteration-invariant pieces
    const int r_a = tid >> 3;           // 0..31
    const int kc  = tid & 7;            // 0..7
    const int wcol = (kc * 8) ^ ((r_a & 7) << 3);
    const size_t gA = (size_t)(r0 + r_a) * DM + kc * 8;
    const size_t gB = (size_t)r_a * 512 + kc * 8;

    // named prefetch registers
    bf16x8 a0h, a1h, a2h, a3h, a0l, a1l, a2l, a3l, b0h, b1h, b0l, b1l;

    #define GLOAD(k0)                                                   \
        a0h = *(const bf16x8*)(Ah_g + gA + (k0));                       \
        a1h = *(const bf16x8*)(Ah_g + gA + 32 * DM + (k0));             \
        a2h = *(const bf16x8*)(Ah_g + gA + 64 * DM + (k0));             \
        a3h = *(const bf16x8*)(Ah_g + gA + 96 * DM + (k0));             \
        a0l = *(const bf16x8*)(Al_g + gA + (k0));                       \
        a1l = *(const bf16x8*)(Al_g + gA + 32 * DM + (k0));             \
        a2l = *(const bf16x8*)(Al_g + gA + 64 * DM + (k0));             \
        a3l = *(const bf16x8*)(Al_g + gA + 96 * DM + (k0));             \
        b0h = *(const bf16x8*)(Bsh + gB + (k0));                        \
        b1h = *(const bf16x8*)(Bsh + gB + 32 * 512 + (k0));             \
        b0l = *(const bf16x8*)(Bsl + gB + (k0));                        \
        b1l = *(const bf16x8*)(Bsl + gB + 32 * 512 + (k0));

    f32x4 acc[2][4];
    #pragma unroll
    for (int i = 0; i < 2; ++i)
        #pragma unroll
        for (int j = 0; j < 4; ++j)
            acc[i][j] = (f32x4){0.f, 0.f, 0.f, 0.f};

    GLOAD(0);

    for (int kt = 0; kt < 8; ++kt) {
        __syncthreads();
        *(bf16x8*)&Ah[r_a][wcol]      = a0h;
        *(bf16x8*)&Ah[r_a + 32][wcol] = a1h;
        *(bf16x8*)&Ah[r_a + 64][wcol] = a2h;
        *(bf16x8*)&Ah[r_a + 96][wcol] = a3h;
        *(bf16x8*)&Al[r_a][wcol]      = a0l;
        *(bf16x8*)&Al[r_a + 32][wcol] = a1l;
        *(bf16x8*)&Al[r_a + 64][wcol] = a2l;
        *(bf16x8*)&Al[r_a + 96][wcol] = a3l;
        *(bf16x8*)&Bh[r_a][wcol]      = b0h;
        *(bf16x8*)&Bh[r_a + 32][wcol] = b1h;
        *(bf16x8*)&Bl[r_a][wcol]      = b0l;
        *(bf16x8*)&Bl[r_a + 32][wcol] = b1l;
        __syncthreads();
        if (kt < 7) { GLOAD((kt + 1) * 64); }

        #pragma unroll
        for (int kk = 0; kk < 2; ++kk) {
            const int fc = (kk * 32 + lg * 8) ^ ((ln & 7) << 3);
            bf16x8 ah[2], al[2], bh2[4], bl2[4];
            #pragma unroll
            for (int ti = 0; ti < 2; ++ti) {
                ah[ti] = *(const bf16x8*)&Ah[w * 32 + ti * 16 + ln][fc];
                al[ti] = *(const bf16x8*)&Al[w * 32 + ti * 16 + ln][fc];
            }
            #pragma unroll
            for (int nj = 0; nj < 4; ++nj) {
                bh2[nj] = *(const bf16x8*)&Bh[nj * 16 + ln][fc];
                bl2[nj] = *(const bf16x8*)&Bl[nj * 16 + ln][fc];
            }
            #pragma unroll
            for (int ti = 0; ti < 2; ++ti)
                #pragma unroll
                for (int nj = 0; nj < 4; ++nj) {
                    acc[ti][nj] = MFMA(ah[ti], bh2[nj], acc[ti][nj]);
                    acc[ti][nj] = MFMA(ah[ti], bl2[nj], acc[ti][nj]);
                    acc[ti][nj] = MFMA(al[ti], bh2[nj], acc[ti][nj]);
                }
        }
    }
    #undef GLOAD

    const float qscale = (mode == 0 && y < 8) ? 0.125f : 1.0f;
    #pragma unroll
    for (int ti = 0; ti < 2; ++ti)
        #pragma unroll
        for (int nj = 0; nj < 4; ++nj)
            #pragma unroll
            for (int r = 0; r < 4; ++r) {
                float val = acc[ti][nj][r] * qscale;
                int t = r0 + w * 32 + ti * 16 + lg * 4 + r;
                int n = nj * 16 + ln;
                if (mode == 0) {
                    int bh = (t >> 12) * NH + (y & 7);
                    size_t off = ((size_t)bh * TSEQ + (t & (TSEQ - 1))) * HS + n;
                    u16 hb = f2bf(val);
                    u16 lb = f2bf(val - bf2f(hb));
                    if (y < 8) { O0h[off] = hb; O0l[off] = lb; }
                    else       { O1h[off] = hb; O1l[off] = lb; }
                } else {
                    Of[(size_t)t * DM + y * 64 + n] = val;
                }
            }
}

// ---------------------------------------------------------------------------
// Banded flash attention. 128 t-rows/block, 4 waves. 48 KB LDS, swizzled,
// staggered conflict-free transpose, V prefetch in named scalar regs.
// ---------------------------------------------------------------------------
__global__ __launch_bounds__(256) void attn_mfma(
    const u16* __restrict__ Qh_g, const u16* __restrict__ Ql_g,
    const u16* __restrict__ Vh_g, const u16* __restrict__ Vl_g,
    u16* __restrict__ Ch, u16* __restrict__ Cl)
{
    __shared__ u16 Vn_h[64][64], Vn_l[64][64];   // [u][s^((u&7)<<3)]
    __shared__ u16 Vt_h[64][64], Vt_l[64][64];   // [s][u^((s&7)<<3)]
    __shared__ unsigned Ps[128][32];             // [t][(u&31)^((t&7)<<2)]

    const int tid = threadIdx.x;
    const int w = tid >> 6, lane = tid & 63;
    const int lg = lane >> 4, ln = lane & 15;
    const int ttile = blockIdx.x & 31;
    const int bh = blockIdx.x >> 5;
    const int t0 = ttile * 128;
    const u16* Qph = Qh_g + (size_t)bh * TSEQ * HS;
    const u16* Qpl = Ql_g + (size_t)bh * TSEQ * HS;
    const u16* Vph = Vh_g + (size_t)bh * TSEQ * HS;
    const u16* Vpl = Vl_g + (size_t)bh * TSEQ * HS;

    // register-resident Q fragments (prescaled by 1/8 in projection)
    bf16x8 qh[2][2], ql[2][2];
    #pragma unroll
    for (int ti = 0; ti < 2; ++ti)
        #pragma unroll
        for (int kk = 0; kk < 2; ++kk) {
            int trow = t0 + w * 32 + ti * 16 + ln;
            size_t off = (size_t)trow * HS + kk * 32 + lg * 8;
            qh[ti][kk] = *(const bf16x8*)(Qph + off);
            ql[ti][kk] = *(const bf16x8*)(Qpl + off);
        }

    f32x4 o[2][4];
    float m[2][4], lsum[2][4];
    #pragma unroll
    for (int ti = 0; ti < 2; ++ti)
        #pragma unroll
        for (int j = 0; j < 4; ++j) {
            o[ti][j] = (f32x4){0.f, 0.f, 0.f, 0.f};
            m[ti][j] = -1e30f;
            lsum[ti][j] = 0.f;
        }

    int u_lo = t0 - CTX; if (u_lo < 0) u_lo = 0;
    int u_hi = t0 + 128 + CTX; if (u_hi > TSEQ) u_hi = TSEQ;

    // staging geometry (iteration-invariant): u = u_r + {0,32}, sc = tid&7
    const int u_r = tid >> 3;           // 0..31
    const int sc  = tid & 7;            // 0..7
    const size_t gV = (size_t)u_r * HS + sc * 8;

    bf16x8 vf0h, vf1h, vf0l, vf1l;       // named prefetch regs
    #define V_LOAD(u0v)                                                   \
        vf0h = *(const bf16x8*)(Vph + (size_t)(u0v) * HS + gV);           \
        vf1h = *(const bf16x8*)(Vph + (size_t)(u0v) * HS + gV + 32 * HS); \
        vf0l = *(const bf16x8*)(Vpl + (size_t)(u0v) * HS + gV);           \
        vf1l = *(const bf16x8*)(Vpl + (size_t)(u0v) * HS + gV + 32 * HS);

    V_LOAD(u_lo);

    const int wcolV = (sc * 8) ^ ((u_r & 7) << 3);

    for (int u0 = u_lo; u0 < u_hi; u0 += 64) {
        __syncthreads();

        // natural layout writes (swizzled b128)
        *(bf16x8*)&Vn_h[u_r][wcolV]      = vf0h;
        *(bf16x8*)&Vn_h[u_r + 32][wcolV] = vf1h;
        *(bf16x8*)&Vn_l[u_r][wcolV]      = vf0l;
        *(bf16x8*)&Vn_l[u_r + 32][wcolV] = vf1l;
        // transposed writes, staggered (conflict-free): row&7 == j
        {
            union { bf16x8 v; ull q[2]; } h0, h1, l0, l1;
            h0.v = vf0h; h1.v = vf1h; l0.v = vf0l; l1.v = vf1l;
            #pragma unroll
            for (int e = 0; e < 8; ++e) {
                int j = (sc + e) & 7;
                int sh = (j & 3) * 16;
                int row = sc * 8 + j;
                ull sh0 = (j & 4) ? h0.q[1] : h0.q[0];
                ull sl0 = (j & 4) ? l0.q[1] : l0.q[0];
                ull sh1 = (j & 4) ? h1.q[1] : h1.q[0];
                ull sl1 = (j & 4) ? l1.q[1] : l1.q[0];
                Vt_h[row][u_r ^ (j << 3)]        = (u16)(sh0 >> sh);
                Vt_l[row][u_r ^ (j << 3)]        = (u16)(sl0 >> sh);
                Vt_h[row][(u_r + 32) ^ (j << 3)] = (u16)(sh1 >> sh);
                Vt_l[row][(u_r + 32) ^ (j << 3)] = (u16)(sl1 >> sh);
            }
        }
        __syncthreads();
        if (u0 + 64 < u_hi) { V_LOAD(u0 + 64); }   // hide HBM under compute

        // scores: S[t][u] = sum_s Q[t][s] V[u][s]
        f32x4 s[2][4];
        #pragma unroll
        for (int ti = 0; ti < 2; ++ti)
            #pragma unroll
            for (int j = 0; j < 4; ++j)
                s[ti][j] = (f32x4){0.f, 0.f, 0.f, 0.f};

        #pragma unroll
        for (int kk = 0; kk < 2; ++kk) {
            const int fc = (kk * 32 + lg * 8) ^ ((ln & 7) << 3);
            bf16x8 vh[4], vl[4];
            #pragma unroll
            for (int uj = 0; uj < 4; ++uj) {
                vh[uj] = *(const bf16x8*)&Vn_h[uj * 16 + ln][fc];
                vl[uj] = *(const bf16x8*)&Vn_l[uj * 16 + ln][fc];
            }
            #pragma unroll
            for (int ti = 0; ti < 2; ++ti)
                #pragma unroll
                for (int uj = 0; uj < 4; ++uj) {
                    s[ti][uj] = MFMA(qh[ti][kk], vh[uj], s[ti][uj]);
                    s[ti][uj] = MFMA(qh[ti][kk], vl[uj], s[ti][uj]);
                    s[ti][uj] = MFMA(ql[ti][kk], vh[uj], s[ti][uj]);
                }
        }

        // band mask
        bool needmask = ((t0 + 127 - u0) > CTX) || ((u0 + 63 - t0) > CTX);
        if (needmask) {
            #pragma unroll
            for (int ti = 0; ti < 2; ++ti)
                #pragma unroll
                for (int uj = 0; uj < 4; ++uj)
                    #pragma unroll
                    for (int r = 0; r < 4; ++r) {
                        int t = t0 + w * 32 + ti * 16 + lg * 4 + r;
                        int u = u0 + uj * 16 + ln;
                        int d = t - u; if (d < 0) d = -d;
                        if (d > CTX) s[ti][uj][r] = -1e30f;
                    }
        }

        // online softmax per row
        float scl[2][4];
        #pragma unroll
        for (int ti = 0; ti < 2; ++ti)
            #pragma unroll
            for (int r = 0; r < 4; ++r) {
                float rm = fmaxf(fmaxf(s[ti][0][r], s[ti][1][r]),
                                 fmaxf(s[ti][2][r], s[ti][3][r]));
                rm = fmaxf(rm, __shfl_xor(rm, 1));
                rm = fmaxf(rm, __shfl_xor(rm, 2));
                rm = fmaxf(rm, __shfl_xor(rm, 4));
                rm = fmaxf(rm, __shfl_xor(rm, 8));
                float mn = fmaxf(m[ti][r], rm);
                float sc2 = __expf(m[ti][r] - mn);
                m[ti][r] = mn;
                scl[ti][r] = sc2;
                float rs = 0.f;
                #pragma unroll
                for (int uj = 0; uj < 4; ++uj) {
                    float p = __expf(s[ti][uj][r] - mn);
                    s[ti][uj][r] = p;
                    rs += p;
                }
                rs += __shfl_xor(rs, 1);
                rs += __shfl_xor(rs, 2);
                rs += __shfl_xor(rs, 4);
                rs += __shfl_xor(rs, 8);
                lsum[ti][r] = lsum[ti][r] * sc2 + rs;
            }

        // rescale running O
        #pragma unroll
        for (int ti = 0; ti < 2; ++ti)
            #pragma unroll
            for (int sj = 0; sj < 4; ++sj)
                #pragma unroll
                for (int r = 0; r < 4; ++r)
                    o[ti][sj][r] *= scl[ti][r];

        // PV in two u-halves; P half-strip written then consumed by same wave
        #pragma unroll
        for (int kk = 0; kk < 2; ++kk) {
            #pragma unroll
            for (int ti = 0; ti < 2; ++ti)
                #pragma unroll
                for (int u2 = 0; u2 < 2; ++u2) {
                    int uj = kk * 2 + u2;
                    #pragma unroll
                    for (int r = 0; r < 4; ++r) {
                        float p = s[ti][uj][r];
                        u16 hb = f2bf(p);
                        u16 lb = f2bf(p - bf2f(hb));
                        int trow = w * 32 + ti * 16 + lg * 4 + r;
                        int ucol = (u2 * 16 + ln) ^ ((trow & 7) << 2);
                        Ps[trow][ucol] = (unsigned)hb | ((unsigned)lb << 16);
                    }
                }

            bf16x8 ph[2], pl[2], vth[4], vtl[4];
            #pragma unroll
            for (int ti = 0; ti < 2; ++ti) {
                int prow = w * 32 + ti * 16 + ln;
                int sw = (ln & 7) << 2;
                uint4 q0 = *(const uint4*)&Ps[prow][(lg * 8) ^ sw];
                uint4 q1 = *(const uint4*)&Ps[prow][(lg * 8 + 4) ^ sw];
                union { unsigned u[4]; bf16x8 v; } H, L;
                H.u[0] = __builtin_amdgcn_perm(q0.y, q0.x, 0x05040100u);
                H.u[1] = __builtin_amdgcn_perm(q0.w, q0.z, 0x05040100u);
                H.u[2] = __builtin_amdgcn_perm(q1.y, q1.x, 0x05040100u);
                H.u[3] = __builtin_amdgcn_perm(q1.w, q1.z, 0x05040100u);
                L.u[0] = __builtin_amdgcn_perm(q0.y, q0.x, 0x07060302u);
                L.u[1] = __builtin_amdgcn_perm(q0.w, q0.z, 0x07060302u);
                L.u[2] = __builtin_amdgcn_perm(q1.y, q1.x, 0x07060302u);
                L.u[3] = __builtin_amdgcn_perm(q1.w, q1.z, 0x07060302u);
                ph[ti] = H.v;
                pl[ti] = L.v;
            }
            const int fct = (kk * 32 + lg * 8) ^ ((ln & 7) << 3);
            #pragma unroll
            for (int sj = 0; sj < 4; ++sj) {
                vth[sj] = *(const bf16x8*)&Vt_h[sj * 16 + ln][fct];
                vtl[sj] = *(const bf16x8*)&Vt_l[sj * 16 + ln][fct];
            }
            #pragma unroll
            for (int ti = 0; ti < 2; ++ti)
                #pragma unroll
                for (int sj = 0; sj < 4; ++sj) {
                    o[ti][sj] = MFMA(ph[ti], vth[sj], o[ti][sj]);
                    o[ti][sj] = MFMA(ph[ti], vtl[sj], o[ti][sj]);
                    o[ti][sj] = MFMA(pl[ti], vth[sj], o[ti][sj]);
                }
        }
    }
    #undef V_LOAD

    // epilogue: C as split bf16, layout [b][t][h*64+s]
    const int b = bh >> 3, h = bh & 7;
    #pragma unroll
    for (int ti = 0; ti < 2; ++ti)
        #pragma unroll
        for (int r = 0; r < 4; ++r) {
            float inv = 1.f / lsum[ti][r];
            int t = t0 + w * 32 + ti * 16 + lg * 4 + r;
            #pragma unroll
            for (int sj = 0; sj < 4; ++sj) {
                int ss = sj * 16 + ln;
                float val = o[ti][sj][r] * inv;
                size_t off = ((size_t)(b * TSEQ + t)) * DM + h * HS + ss;
                u16 hb = f2bf(val);
                Ch[off] = hb;
                Cl[off] = f2bf(val - bf2f(hb));
            }
        }
}

// ---------------------------------------------------------------------------
extern "C" void kernel_launch(void* const* d_in, const int* in_sizes, int n_in,
                              void* d_out, int out_size, void* d_ws, size_t ws_size,
                              hipStream_t stream) {
    const float* X  = (const float*)d_in[0];
    const float* WQ = (const float*)d_in[1];
    const float* WV = (const float*)d_in[2];
    const float* WU = (const float*)d_in[3];
    float* out = (float*)d_out;

    const size_t SZ = 8388608;   // 8 MB region
    char* ws = (char*)d_ws;
    u16* Xh = (u16*)(ws);             // later reused as Ch
    u16* Xl = (u16*)(ws + SZ);        // later reused as Cl
    u16* Qh = (u16*)(ws + 2 * SZ);
    u16* Ql = (u16*)(ws + 3 * SZ);
    u16* Vh = (u16*)(ws + 4 * SZ);
    u16* Vl = (u16*)(ws + 5 * SZ);
    char* wsw = ws + 6 * SZ;
    u16* WQt_h = (u16*)(wsw);
    u16* WQt_l = (u16*)(wsw + 524288);
    u16* WVt_h = (u16*)(wsw + 2 * 524288);
    u16* WVt_l = (u16*)(wsw + 3 * 524288);
    u16* WUt_h = (u16*)(wsw + 4 * 524288);
    u16* WUt_l = (u16*)(wsw + 5 * 524288);

    presplit_x<<<2048, 256, 0, stream>>>(X, Xh, Xl);
    presplit_w<<<3072, 256, 0, stream>>>(WQ, WV, WU, WQt_h, WQt_l,
                                         WVt_h, WVt_l, WUt_h, WUt_l);
    gemm_mfma<<<dim3(64, 16), 256, 0, stream>>>(
        Xh, Xl, WQt_h, WQt_l, WVt_h, WVt_l, Qh, Ql, Vh, Vl, nullptr, 0);
    attn_mfma<<<dim3(512), 256, 0, stream>>>(Qh, Ql, Vh, Vl, Xh, Xl);
    gemm_mfma<<<dim3(64, 8), 256, 0, stream>>>(
        Xh, Xl, WUt_h, WUt_l, nullptr, nullptr,
        nullptr, nullptr, nullptr, nullptr, out, 1);
}